// Round 1
// baseline (124.720 us; speedup 1.0000x reference)
//
#include <hip/hip_runtime.h>

#define N_ROWS 4096
#define D_K    2048
#define BM 128
#define BN 128
#define BK 32
#define MARGIN 0.3f

typedef unsigned short u16;
typedef __attribute__((ext_vector_type(8))) short bf16x8;
typedef __attribute__((ext_vector_type(4))) float f32x4;

#define GLOAD_LDS16(g, l) __builtin_amdgcn_global_load_lds( \
    (const __attribute__((address_space(1))) unsigned int*)(g), \
    (__attribute__((address_space(3))) unsigned int*)(l), 16, 0, 0)

__device__ __forceinline__ u16 f2bf(float f) {
    unsigned u = __float_as_uint(f);
    u += 0x7fffu + ((u >> 16) & 1u);   // round-to-nearest-even
    return (u16)(u >> 16);
}

// ---------- Kernel 1: fp32 -> bf16 convert, exact fp32 row norms, init ap2/an2 ----------
__global__ __launch_bounds__(256) void prep_kernel(
    const float* __restrict__ emb, u16* __restrict__ embB,
    float* __restrict__ xx, unsigned* __restrict__ ap2, unsigned* __restrict__ an2)
{
    const int row = blockIdx.x;
    const int t = threadIdx.x;
    const float4* src = (const float4*)(emb + (size_t)row * D_K);
    ushort4* dst = (ushort4*)(embB + (size_t)row * D_K);
    float s = 0.f;
#pragma unroll
    for (int i = 0; i < 2; ++i) {
        float4 v = src[t + i * 256];
        s = fmaf(v.x, v.x, s);
        s = fmaf(v.y, v.y, s);
        s = fmaf(v.z, v.z, s);
        s = fmaf(v.w, v.w, s);
        ushort4 o;
        o.x = f2bf(v.x); o.y = f2bf(v.y); o.z = f2bf(v.z); o.w = f2bf(v.w);
        dst[t + i * 256] = o;
    }
#pragma unroll
    for (int off = 32; off >= 1; off >>= 1) s += __shfl_down(s, off, 64);
    __shared__ float red[4];
    if ((t & 63) == 0) red[t >> 6] = s;
    __syncthreads();
    if (t == 0) {
        xx[row] = red[0] + red[1] + red[2] + red[3];
        ap2[row] = 0u;            // float 0.0
        an2[row] = 0x7f7fffffu;   // FLT_MAX
    }
}

// ---------- Kernel 2: fused bf16 MFMA gram tile + masked max/min reduction ----------
__global__ __launch_bounds__(256) void gram_reduce_kernel(
    const u16* __restrict__ embB, const float* __restrict__ xx,
    const int* __restrict__ lab, unsigned* __restrict__ ap2, unsigned* __restrict__ an2)
{
    __shared__ u16 As[BM * BK];
    __shared__ u16 Bs[BN * BK];
    __shared__ int labR[BM], labC[BN];
    __shared__ float xxR[BM], xxC[BN];

    const int bm = blockIdx.y, bn = blockIdx.x;
    const int row0 = bm * BM, col0 = bn * BN;
    const int t = threadIdx.x;

    if (t < 128) { labR[t] = lab[row0 + t]; xxR[t] = xx[row0 + t]; }
    else         { int u = t - 128; labC[u] = lab[col0 + u]; xxC[u] = xx[col0 + u]; }

    f32x4 acc[4][4];
#pragma unroll
    for (int m = 0; m < 4; ++m)
#pragma unroll
        for (int n = 0; n < 4; ++n) acc[m][n] = (f32x4){0.f, 0.f, 0.f, 0.f};

    const int l = t & 63, w = t >> 6;
    const int wr = w >> 1, wc = w & 1;
    const int fr = l & 15, fkb = l >> 4;   // fragment row / k-block

    // staging addresses: thread t -> row t/4 (of 64), 8 elems at col (t%4)*8
    const int rowIn = t >> 2;
    const int colB = (t & 3) * 8;
    const u16* gA0 = embB + (size_t)(row0 + rowIn) * D_K + colB;
    const u16* gB0 = embB + (size_t)(col0 + rowIn) * D_K + colB;
    u16* lA0 = &As[rowIn * BK + colB];
    u16* lA1 = &As[(rowIn + 64) * BK + colB];
    u16* lB0 = &Bs[rowIn * BK + colB];
    u16* lB1 = &Bs[(rowIn + 64) * BK + colB];
    const size_t rstep = (size_t)64 * D_K;

    for (int kt = 0; kt < D_K; kt += BK) {
        GLOAD_LDS16(gA0 + kt,         lA0);
        GLOAD_LDS16(gA0 + kt + rstep, lA1);
        GLOAD_LDS16(gB0 + kt,         lB0);
        GLOAD_LDS16(gB0 + kt + rstep, lB1);
        __syncthreads();   // drains vmcnt: staged tile visible

        bf16x8 aF[4], bF[4];
#pragma unroll
        for (int m = 0; m < 4; ++m)
            aF[m] = *(const bf16x8*)&As[(wr * 64 + m * 16 + fr) * BK + fkb * 8];
#pragma unroll
        for (int n = 0; n < 4; ++n)
            bF[n] = *(const bf16x8*)&Bs[(wc * 64 + n * 16 + fr) * BK + fkb * 8];
#pragma unroll
        for (int m = 0; m < 4; ++m)
#pragma unroll
            for (int n = 0; n < 4; ++n)
                acc[m][n] = __builtin_amdgcn_mfma_f32_16x16x32_bf16(aF[m], bF[n], acc[m][n], 0, 0, 0);
        __syncthreads();   // all reads done before next stage overwrites
    }

    // epilogue: d2 = xx_i + xx_j - 2g, clamp, masked max/min, reduce over 16 cols
    const int rgrp = l >> 4;
#pragma unroll
    for (int m = 0; m < 4; ++m) {
#pragma unroll
        for (int r = 0; r < 4; ++r) {
            const int il = wr * 64 + m * 16 + rgrp * 4 + r;   // C/D row = (lane>>4)*4 + reg
            const int li = labR[il];
            const float xi = xxR[il];
            float apv = 0.f, anv = __FLT_MAX__;
#pragma unroll
            for (int n = 0; n < 4; ++n) {
                const int jl = wc * 64 + n * 16 + fr;          // C/D col = lane&15
                float d2 = xi + xxC[jl] - 2.f * acc[m][n][r];
                d2 = fmaxf(d2, 1e-12f);
                const bool same = (labC[jl] == li);
                apv = same ? fmaxf(apv, d2) : apv;
                anv = same ? anv : fminf(anv, d2);
            }
#pragma unroll
            for (int off = 1; off < 16; off <<= 1) {
                apv = fmaxf(apv, __shfl_xor(apv, off, 64));
                anv = fminf(anv, __shfl_xor(anv, off, 64));
            }
            if (fr == 0) {
                atomicMax(&ap2[row0 + il], __float_as_uint(apv));
                atomicMin(&an2[row0 + il], __float_as_uint(anv));
            }
        }
    }
}

// ---------- Kernel 3: finalize loss + precision ----------
__global__ __launch_bounds__(256) void finalize_kernel(
    const unsigned* __restrict__ ap2, const unsigned* __restrict__ an2, float* __restrict__ out)
{
    const int t = threadIdx.x;
    float ls = 0.f, ps = 0.f;
    for (int i = t; i < N_ROWS; i += 256) {
        const float ap = sqrtf(__uint_as_float(ap2[i]));
        const float an = sqrtf(__uint_as_float(an2[i]));
        ls += fmaxf(MARGIN - an + ap, 0.f);
        ps += (an > ap) ? 1.f : 0.f;
    }
#pragma unroll
    for (int off = 32; off >= 1; off >>= 1) {
        ls += __shfl_down(ls, off, 64);
        ps += __shfl_down(ps, off, 64);
    }
    __shared__ float rl[4], rp[4];
    if ((t & 63) == 0) { rl[t >> 6] = ls; rp[t >> 6] = ps; }
    __syncthreads();
    if (t == 0) {
        out[0] = (rl[0] + rl[1] + rl[2] + rl[3]) * (1.f / N_ROWS);
        out[1] = (rp[0] + rp[1] + rp[2] + rp[3]) * (1.f / N_ROWS);
    }
}

extern "C" void kernel_launch(void* const* d_in, const int* in_sizes, int n_in,
                              void* d_out, int out_size, void* d_ws, size_t ws_size,
                              hipStream_t stream)
{
    const float* emb = (const float*)d_in[0];
    const int* lab = (const int*)d_in[1];
    float* out = (float*)d_out;

    char* ws = (char*)d_ws;
    u16* embB   = (u16*)ws;                                           // 16 MB
    float* xx   = (float*)(ws + (size_t)N_ROWS * D_K * 2);            // 16 KB
    unsigned* ap2 = (unsigned*)(ws + (size_t)N_ROWS * D_K * 2 + N_ROWS * 4);
    unsigned* an2 = (unsigned*)(ws + (size_t)N_ROWS * D_K * 2 + 2 * (size_t)N_ROWS * 4);

    prep_kernel<<<N_ROWS, 256, 0, stream>>>(emb, embB, xx, ap2, an2);
    dim3 grid(N_ROWS / BN, N_ROWS / BM);
    gram_reduce_kernel<<<grid, 256, 0, stream>>>(embB, xx, lab, ap2, an2);
    finalize_kernel<<<1, 256, 0, stream>>>(ap2, an2, out);
}

// Round 2
// 89.763 us; speedup vs baseline: 1.3894x; 1.3894x over previous
//
#include <hip/hip_runtime.h>

#define N_ROWS 4096
#define D_K    2048
#define BM 256
#define BK 64
#define NT (D_K / BK)   // 32 K-tiles
#define MARGIN 0.3f

typedef unsigned short u16;
typedef __attribute__((ext_vector_type(8))) short bf16x8;
typedef __attribute__((ext_vector_type(4))) float f32x4;

__device__ __forceinline__ void stage16(const u16* src, u16* dst) {
    __builtin_amdgcn_global_load_lds((const __attribute__((address_space(1))) unsigned int*)src,
                                     (__attribute__((address_space(3))) unsigned int*)dst, 16, 0, 0);
}

__device__ __forceinline__ u16 f2bf(float f) {
    unsigned u = __float_as_uint(f);
    u += 0x7fffu + ((u >> 16) & 1u);   // round-to-nearest-even
    return (u16)(u >> 16);
}

// ---------- Kernel 1: fp32 -> bf16 convert, exact fp32 row norms, init ap2/an2 ----------
__global__ __launch_bounds__(256) void prep_kernel(
    const float* __restrict__ emb, u16* __restrict__ embB,
    float* __restrict__ xx, unsigned* __restrict__ ap2, unsigned* __restrict__ an2)
{
    const int row = blockIdx.x;
    const int t = threadIdx.x;
    const float4* src = (const float4*)(emb + (size_t)row * D_K);
    ushort4* dst = (ushort4*)(embB + (size_t)row * D_K);
    float s = 0.f;
#pragma unroll
    for (int i = 0; i < 2; ++i) {
        float4 v = src[t + i * 256];
        s = fmaf(v.x, v.x, s);
        s = fmaf(v.y, v.y, s);
        s = fmaf(v.z, v.z, s);
        s = fmaf(v.w, v.w, s);
        ushort4 o;
        o.x = f2bf(v.x); o.y = f2bf(v.y); o.z = f2bf(v.z); o.w = f2bf(v.w);
        dst[t + i * 256] = o;
    }
#pragma unroll
    for (int off = 32; off >= 1; off >>= 1) s += __shfl_down(s, off, 64);
    __shared__ float red[4];
    if ((t & 63) == 0) red[t >> 6] = s;
    __syncthreads();
    if (t == 0) {
        xx[row] = red[0] + red[1] + red[2] + red[3];
        ap2[row] = 0u;            // float 0.0
        an2[row] = 0x7f7fffffu;   // FLT_MAX
    }
}

// ---------- Kernel 2: 256^2 8-phase MFMA gram + fused masked max/min reduction ----------
#define MM(mi, ni, ai, bi) \
    acc[mi][ni] = __builtin_amdgcn_mfma_f32_16x16x32_bf16(aq[ai][0], bq[bi][0], acc[mi][ni], 0, 0, 0); \
    acc[mi][ni] = __builtin_amdgcn_mfma_f32_16x16x32_bf16(aq[ai][1], bq[bi][1], acc[mi][ni], 0, 0, 0);

#define LDv(p) (*(const bf16x8*)(p))

// A chunk (h in 0..1 half, c in 0..1 sub-chunk of 64 rows), B chunk q in 0..3 (64 rows each)
#define STAGE_A(b, h, c, kt) stage16(gA + ((h) * 2 + (c)) * g64 + (kt), lA + (((b) * 256 + (h) * 128 + (c) * 64) * 64))
#define STAGE_B(b, q, kt)    stage16(gB + (q) * g64 + (kt),             lB + (((b) * 256 + (q) * 64) * 64))

#define BARRIER()  __builtin_amdgcn_s_barrier()
#define LGKM0()    asm volatile("s_waitcnt lgkmcnt(0)" ::: "memory")

__global__ __launch_bounds__(512, 2) void gram_reduce_kernel(
    const u16* __restrict__ embB, const float* __restrict__ xx,
    const int* __restrict__ lab, unsigned* __restrict__ ap2, unsigned* __restrict__ an2)
{
    __shared__ u16 Ash[2 * BM * BK];   // 64 KiB, [buf][256 rows][64 cols], swizzled 16B slots
    __shared__ u16 Bsh[2 * BM * BK];   // 64 KiB
    __shared__ int labR[BM], labC[BM];
    __shared__ float xxR[BM], xxC[BM];

    const int tid = threadIdx.x;
    const int bid = blockIdx.x;
    const int swz = (bid & 7) * 32 + (bid >> 3);   // bijective: 256 % 8 == 0
    const int bm = swz >> 4, bn = swz & 15;
    const int row0 = bm * BM, col0 = bn * BM;

    if (tid < 256) { labR[tid] = lab[row0 + tid]; xxR[tid] = xx[row0 + tid]; }
    else           { int u2 = tid - 256; labC[u2] = lab[col0 + u2]; xxC[u2] = xx[col0 + u2]; }
    // drain the lab/xx loads so steady-state vmcnt counting sees only stage ops
    asm volatile("s_waitcnt vmcnt(0) lgkmcnt(0)" ::: "memory");

    // ---- staging constants: linear LDS dest (base + tid*16B), pre-swizzled global source
    const int csw = ((tid & 7) ^ ((tid >> 3) & 7)) * 8;      // involution: slot ^ (row&7)
    const u16* gA = embB + (size_t)(row0 + (tid >> 3)) * D_K + csw;
    const u16* gB = embB + (size_t)(col0 + (tid >> 3)) * D_K + csw;
    u16* lA = Ash + tid * 8;
    u16* lB = Bsh + tid * 8;
    const size_t g64 = (size_t)64 * D_K;

    // ---- fragment-read constants
    const int l = tid & 63, w = tid >> 6;
    const int wr = w >> 2, wc = w & 3;          // 2 x 4 wave grid, per-wave 128x64
    const int fr = l & 15, fkb = l >> 4;        // frag row / k-block
    const int frs = fr & 7;
    const int kx0 = (fkb ^ frs) * 16;           // swizzled k-offset bytes, ks=0
    const int kx1 = kx0 ^ 64;                   // ks=1
    const char* AB = (const char*)Ash;
    const char* BB = (const char*)Bsh;
    const int aOff = wr * 16384 + fr * 128;                      // + buf*32768 + m*2048
    const int bOff = (wc >> 1) * 16384 + ((wc & 1) * 64 + fr) * 128;  // + buf*32768 + n*2048

    f32x4 acc[8][4];
#pragma unroll
    for (int m = 0; m < 8; ++m)
#pragma unroll
        for (int n = 0; n < 4; ++n) acc[m][n] = (f32x4){0.f, 0.f, 0.f, 0.f};

    // ---- prologue: tile 0 fully staged; leave A-chunk1(0) in flight
    STAGE_A(0, 0, 0, 0); STAGE_A(0, 1, 0, 0);
    STAGE_B(0, 0, 0); STAGE_B(0, 1, 0); STAGE_B(0, 2, 0); STAGE_B(0, 3, 0);
    STAGE_A(0, 0, 1, 0); STAGE_A(0, 1, 1, 0);
    asm volatile("s_waitcnt vmcnt(2)" ::: "memory");
    BARRIER();

    for (int t = 0; t < NT; ++t) {
        const int buf = t & 1, nb = buf ^ 1;
        const int bo = buf * 32768;
        const int kt1 = (t + 1) * BK;
        const bool ok = (t + 1 < NT);
        bf16x8 aq[4][2], bq[2][2];

        // ======== phase 0: read A m0-3 + B n0-1 (12 ds_read_b128); stage A-c0(t+1)
#pragma unroll
        for (int m = 0; m < 4; ++m) {
            aq[m][0] = LDv(AB + bo + aOff + m * 2048 + kx0);
            aq[m][1] = LDv(AB + bo + aOff + m * 2048 + kx1);
        }
#pragma unroll
        for (int n = 0; n < 2; ++n) {
            bq[n][0] = LDv(BB + bo + bOff + n * 2048 + kx0);
            bq[n][1] = LDv(BB + bo + bOff + n * 2048 + kx1);
        }
        if (ok) { STAGE_A(nb, 0, 0, kt1); STAGE_A(nb, 1, 0, kt1); }
        BARRIER(); LGKM0();
        __builtin_amdgcn_s_setprio(1);
        MM(0, 0, 0, 0) MM(1, 1, 1, 1) MM(2, 0, 2, 0) MM(3, 1, 3, 1)
        MM(0, 1, 0, 1) MM(1, 0, 1, 0) MM(2, 1, 2, 1) MM(3, 0, 3, 0)
        __builtin_amdgcn_s_setprio(0);
        BARRIER();

        // ======== phase 1: read B n2-3 (4); stage B-q0,q1(t+1); publish A-c1(t) via vmcnt(4)
#pragma unroll
        for (int n = 0; n < 2; ++n) {
            bq[n][0] = LDv(BB + bo + bOff + (n + 2) * 2048 + kx0);
            bq[n][1] = LDv(BB + bo + bOff + (n + 2) * 2048 + kx1);
        }
        if (ok) { STAGE_B(nb, 0, kt1); STAGE_B(nb, 1, kt1); }
        BARRIER(); LGKM0();
        __builtin_amdgcn_s_setprio(1);
        MM(0, 2, 0, 0) MM(1, 3, 1, 1) MM(2, 2, 2, 0) MM(3, 3, 3, 1)
        MM(0, 3, 0, 1) MM(1, 2, 1, 0) MM(2, 3, 2, 1) MM(3, 2, 3, 0)
        __builtin_amdgcn_s_setprio(0);
        if (ok) { asm volatile("s_waitcnt vmcnt(4)" ::: "memory"); }
        else    { asm volatile("s_waitcnt vmcnt(0)" ::: "memory"); }
        BARRIER();

        // ======== phase 2: read A m4-7 (8); stage B-q2,q3(t+1)
#pragma unroll
        for (int m = 0; m < 4; ++m) {
            aq[m][0] = LDv(AB + bo + aOff + (m + 4) * 2048 + kx0);
            aq[m][1] = LDv(AB + bo + aOff + (m + 4) * 2048 + kx1);
        }
        if (ok) { STAGE_B(nb, 2, kt1); STAGE_B(nb, 3, kt1); }
        BARRIER(); LGKM0();
        __builtin_amdgcn_s_setprio(1);
        MM(4, 2, 0, 0) MM(5, 3, 1, 1) MM(6, 2, 2, 0) MM(7, 3, 3, 1)
        MM(4, 3, 0, 1) MM(5, 2, 1, 0) MM(6, 3, 2, 1) MM(7, 2, 3, 0)
        __builtin_amdgcn_s_setprio(0);
        BARRIER();

        // ======== phase 3: re-read B n0-1 (4); stage A-c1(t+1); publish tile t+1 via vmcnt(2)
#pragma unroll
        for (int n = 0; n < 2; ++n) {
            bq[n][0] = LDv(BB + bo + bOff + n * 2048 + kx0);
            bq[n][1] = LDv(BB + bo + bOff + n * 2048 + kx1);
        }
        if (ok) { STAGE_A(nb, 0, 1, kt1); STAGE_A(nb, 1, 1, kt1); }
        BARRIER(); LGKM0();
        __builtin_amdgcn_s_setprio(1);
        MM(4, 0, 0, 0) MM(5, 1, 1, 1) MM(6, 0, 2, 0) MM(7, 1, 3, 1)
        MM(4, 1, 0, 1) MM(5, 0, 1, 0) MM(6, 1, 2, 1) MM(7, 0, 3, 0)
        __builtin_amdgcn_s_setprio(0);
        if (ok) { asm volatile("s_waitcnt vmcnt(2)" ::: "memory"); }
        else    { asm volatile("s_waitcnt vmcnt(0)" ::: "memory"); }
        BARRIER();
    }

    // ---- epilogue: d2 = xx_i + xx_j - 2g, clamp, masked max/min, 16-lane reduce, atomics
    const int rgrp = l >> 4;
#pragma unroll
    for (int m = 0; m < 8; ++m) {
#pragma unroll
        for (int r = 0; r < 4; ++r) {
            const int il = wr * 128 + m * 16 + rgrp * 4 + r;   // C/D row = (lane>>4)*4 + reg
            const int li = labR[il];
            const float xi = xxR[il];
            float apv = 0.f, anv = __FLT_MAX__;
#pragma unroll
            for (int n = 0; n < 4; ++n) {
                const int jl = wc * 64 + n * 16 + fr;          // C/D col = lane&15
                float d2 = xi + xxC[jl] - 2.f * acc[m][n][r];
                d2 = fmaxf(d2, 1e-12f);
                const bool same = (labC[jl] == li);
                apv = same ? fmaxf(apv, d2) : apv;
                anv = same ? anv : fminf(anv, d2);
            }
#pragma unroll
            for (int off = 1; off < 16; off <<= 1) {
                apv = fmaxf(apv, __shfl_xor(apv, off, 64));
                anv = fminf(anv, __shfl_xor(anv, off, 64));
            }
            if (fr == 0) {
                atomicMax(&ap2[row0 + il], __float_as_uint(apv));
                atomicMin(&an2[row0 + il], __float_as_uint(anv));
            }
        }
    }
}

// ---------- Kernel 3: finalize loss + precision ----------
__global__ __launch_bounds__(256) void finalize_kernel(
    const unsigned* __restrict__ ap2, const unsigned* __restrict__ an2, float* __restrict__ out)
{
    const int t = threadIdx.x;
    float ls = 0.f, ps = 0.f;
    for (int i = t; i < N_ROWS; i += 256) {
        const float ap = sqrtf(__uint_as_float(ap2[i]));
        const float an = sqrtf(__uint_as_float(an2[i]));
        ls += fmaxf(MARGIN - an + ap, 0.f);
        ps += (an > ap) ? 1.f : 0.f;
    }
#pragma unroll
    for (int off = 32; off >= 1; off >>= 1) {
        ls += __shfl_down(ls, off, 64);
        ps += __shfl_down(ps, off, 64);
    }
    __shared__ float rl[4], rp[4];
    if ((t & 63) == 0) { rl[t >> 6] = ls; rp[t >> 6] = ps; }
    __syncthreads();
    if (t == 0) {
        out[0] = (rl[0] + rl[1] + rl[2] + rl[3]) * (1.f / N_ROWS);
        out[1] = (rp[0] + rp[1] + rp[2] + rp[3]) * (1.f / N_ROWS);
    }
}

extern "C" void kernel_launch(void* const* d_in, const int* in_sizes, int n_in,
                              void* d_out, int out_size, void* d_ws, size_t ws_size,
                              hipStream_t stream)
{
    const float* emb = (const float*)d_in[0];
    const int* lab = (const int*)d_in[1];
    float* out = (float*)d_out;

    char* ws = (char*)d_ws;
    u16* embB   = (u16*)ws;                                           // 16 MB
    float* xx   = (float*)(ws + (size_t)N_ROWS * D_K * 2);
    unsigned* ap2 = (unsigned*)(ws + (size_t)N_ROWS * D_K * 2 + N_ROWS * 4);
    unsigned* an2 = (unsigned*)(ws + (size_t)N_ROWS * D_K * 2 + 2 * (size_t)N_ROWS * 4);

    prep_kernel<<<N_ROWS, 256, 0, stream>>>(emb, embB, xx, ap2, an2);
    dim3 grid((N_ROWS / BM) * (N_ROWS / BM));   // 16*16 = 256 blocks, 1 per CU
    gram_reduce_kernel<<<grid, 512, 0, stream>>>(embB, xx, lab, ap2, an2);
    finalize_kernel<<<1, 256, 0, stream>>>(ap2, an2, out);
}